// Round 1
// baseline (25324.745 us; speedup 1.0000x reference)
//
#include <hip/hip_runtime.h>
#include <math.h>

// ---------------------------------------------------------------------------
// SDTP model forward, round 1: all-fp32 correctness-first implementation.
// V=32000 D=2048 L=4 H=16 FF=8192 B=2 S=2048 DH=128, prune@layers{1,2} keep 50%.
// ---------------------------------------------------------------------------

#define DD     2048
#define HH     16
#define DHH    128
#define FFF    8192
#define BBATCH 2
#define SSEQ   2048
#define VV     32000
#define LLAYERS 4

typedef float4 f4;

// ---------------- embedding gather ----------------
__global__ void k_embed(const int* __restrict__ ids, const float* __restrict__ emb,
                        float* __restrict__ out) {
    int row = blockIdx.x;               // 0..B*S-1
    int id  = ids[row];
    const f4* src = (const f4*)(emb + (size_t)id * DD);
    f4*       dst = (f4*)(out + (size_t)row * DD);
    for (int i = threadIdx.x; i < DD / 4; i += blockDim.x) dst[i] = src[i];
}

__global__ void k_copy_int(const int* __restrict__ src, int* __restrict__ dst, int n) {
    int i = blockIdx.x * blockDim.x + threadIdx.x;
    if (i < n) dst[i] = src[i];
}

__global__ void k_copyf4(const float* __restrict__ src, float* __restrict__ dst, long n4) {
    long i = (long)blockIdx.x * blockDim.x + threadIdx.x;
    if (i < n4) ((f4*)dst)[i] = ((const f4*)src)[i];
}

// ---------------- rmsnorm ----------------
__global__ __launch_bounds__(256) void k_rmsnorm(const float* __restrict__ x,
                                                 const float* __restrict__ w,
                                                 float* __restrict__ out) {
    int row = blockIdx.x;
    const float* xr = x + (size_t)row * DD;
    float ss = 0.f;
    for (int i = threadIdx.x; i < DD / 4; i += blockDim.x) {
        f4 v = ((const f4*)xr)[i];
        ss += v.x * v.x + v.y * v.y + v.z * v.z + v.w * v.w;
    }
    for (int o = 32; o > 0; o >>= 1) ss += __shfl_down(ss, o);
    __shared__ float red[4];
    int wid = threadIdx.x >> 6, lane = threadIdx.x & 63;
    if (lane == 0) red[wid] = ss;
    __syncthreads();
    float tot = red[0] + red[1] + red[2] + red[3];
    float inv = 1.0f / sqrtf(tot / (float)DD + 1e-6f);
    float* orow = out + (size_t)row * DD;
    for (int i = threadIdx.x; i < DD / 4; i += blockDim.x) {
        f4 v = ((const f4*)xr)[i];
        f4 wv = ((const f4*)w)[i];
        f4 o;
        o.x = v.x * wv.x * inv; o.y = v.y * wv.y * inv;
        o.z = v.z * wv.z * inv; o.w = v.w * wv.w * inv;
        ((f4*)orow)[i] = o;
    }
}

// ---------------- fp32 GEMM: C = A[MxK] @ W[KxN] (+R) ----------------
// M,N multiples of 64; K multiple of 16.
template <int RES>
__global__ __launch_bounds__(256) void k_gemm(const float* __restrict__ A,
                                              const float* __restrict__ W,
                                              const float* __restrict__ R,
                                              float* __restrict__ C,
                                              int M, int N, int K) {
    __shared__ float As[16][65];
    __shared__ float Bs[16][68];
    int tid = threadIdx.x;
    int tx = tid & 15, ty = tid >> 4;
    int m0 = blockIdx.y * 64, n0 = blockIdx.x * 64;
    float acc[4][4] = {};
    for (int k0 = 0; k0 < K; k0 += 16) {
        {   // A tile 64x16
            int ar = tid >> 2, ac = (tid & 3) * 4;
            f4 av = *(const f4*)(A + (size_t)(m0 + ar) * K + k0 + ac);
            As[ac + 0][ar] = av.x; As[ac + 1][ar] = av.y;
            As[ac + 2][ar] = av.z; As[ac + 3][ar] = av.w;
        }
        {   // W tile 16x64
            int br = tid >> 4, bc = (tid & 15) * 4;
            *(f4*)&Bs[br][bc] = *(const f4*)(W + (size_t)(k0 + br) * N + n0 + bc);
        }
        __syncthreads();
#pragma unroll
        for (int kk = 0; kk < 16; kk++) {
            float a[4], b[4];
#pragma unroll
            for (int i = 0; i < 4; i++) a[i] = As[kk][ty * 4 + i];
#pragma unroll
            for (int j = 0; j < 4; j++) b[j] = Bs[kk][tx * 4 + j];
#pragma unroll
            for (int i = 0; i < 4; i++)
#pragma unroll
                for (int j = 0; j < 4; j++) acc[i][j] += a[i] * b[j];
        }
        __syncthreads();
    }
#pragma unroll
    for (int i = 0; i < 4; i++) {
        int m = m0 + ty * 4 + i;
        float* crow = C + (size_t)m * N + n0;
        const float* rrow = R + (size_t)m * N + n0;
#pragma unroll
        for (int j = 0; j < 4; j++) {
            float v = acc[i][j];
            if (RES) v += rrow[tx * 4 + j];
            crow[tx * 4 + j] = v;
        }
    }
}

// ---------------- dual GEMM + SwiGLU: out = silu(A@Wg) * (A@Wu) ----------------
__global__ __launch_bounds__(256) void k_gemm_dual(const float* __restrict__ A,
                                                   const float* __restrict__ Wg,
                                                   const float* __restrict__ Wu,
                                                   float* __restrict__ Cout,
                                                   int M, int N, int K) {
    __shared__ float As[16][65];
    __shared__ float Bg[16][68];
    __shared__ float Bu[16][68];
    int tid = threadIdx.x;
    int tx = tid & 15, ty = tid >> 4;
    int m0 = blockIdx.y * 64, n0 = blockIdx.x * 64;
    float ag[4][4] = {}, au[4][4] = {};
    for (int k0 = 0; k0 < K; k0 += 16) {
        {
            int ar = tid >> 2, ac = (tid & 3) * 4;
            f4 av = *(const f4*)(A + (size_t)(m0 + ar) * K + k0 + ac);
            As[ac + 0][ar] = av.x; As[ac + 1][ar] = av.y;
            As[ac + 2][ar] = av.z; As[ac + 3][ar] = av.w;
        }
        {
            int br = tid >> 4, bc = (tid & 15) * 4;
            *(f4*)&Bg[br][bc] = *(const f4*)(Wg + (size_t)(k0 + br) * N + n0 + bc);
            *(f4*)&Bu[br][bc] = *(const f4*)(Wu + (size_t)(k0 + br) * N + n0 + bc);
        }
        __syncthreads();
#pragma unroll
        for (int kk = 0; kk < 16; kk++) {
            float a[4], bg[4], bu[4];
#pragma unroll
            for (int i = 0; i < 4; i++) a[i] = As[kk][ty * 4 + i];
#pragma unroll
            for (int j = 0; j < 4; j++) { bg[j] = Bg[kk][tx * 4 + j]; bu[j] = Bu[kk][tx * 4 + j]; }
#pragma unroll
            for (int i = 0; i < 4; i++)
#pragma unroll
                for (int j = 0; j < 4; j++) { ag[i][j] += a[i] * bg[j]; au[i][j] += a[i] * bu[j]; }
        }
        __syncthreads();
    }
#pragma unroll
    for (int i = 0; i < 4; i++) {
        int m = m0 + ty * 4 + i;
        float* crow = Cout + (size_t)m * N + n0;
#pragma unroll
        for (int j = 0; j < 4; j++) {
            float g = ag[i][j], u = au[i][j];
            float sg = g / (1.0f + expf(-g));
            crow[tx * 4 + j] = sg * u;
        }
    }
}

// ---------------- RoPE table (match numpy fp32 dataflow) ----------------
__global__ void k_rope_table(float* __restrict__ cosT, float* __restrict__ sinT) {
    int idx = blockIdx.x * blockDim.x + threadIdx.x;
    if (idx >= SSEQ * 64) return;
    int pos = idx >> 6, d = idx & 63;
    // np: inv = 1.0f / powf(10000.0f, d/64.0f) with correctly-rounded powf.
    float p   = (float)pow(10000.0, (double)d * (1.0 / 64.0));
    float inv = 1.0f / p;
    float ang = (float)pos * inv;   // fp32 multiply, bit-identical to np
    cosT[idx] = (float)cos((double)ang);
    sinT[idx] = (float)sin((double)ang);
}

// ---------------- RoPE in-place on Q,K projections ((b,s) rows, per head) ------
__global__ void k_rope(float* __restrict__ Cq, float* __restrict__ Ck,
                       const float* __restrict__ cosT, const float* __restrict__ sinT,
                       int s) {
    int bi = blockIdx.x;            // b*s*H
    int h = bi % HH;
    int i = (bi / HH) % s;
    size_t base = (size_t)(bi / HH) * DD + h * DHH;
    int d = threadIdx.x;            // 0..63
    float c  = cosT[i * 64 + d];
    float sn = sinT[i * 64 + d];
    float x1 = Cq[base + d], x2 = Cq[base + 64 + d];
    Cq[base + d]      = x1 * c - x2 * sn;
    Cq[base + 64 + d] = x1 * sn + x2 * c;
    x1 = Ck[base + d]; x2 = Ck[base + 64 + d];
    Ck[base + d]      = x1 * c - x2 * sn;
    Ck[base + 64 + d] = x1 * sn + x2 * c;
}

// ---------------- flash attention fp32 ----------------
// Q,K,V,O in (b*s, H*DH) row layout; head slice contiguous 128 floats.
// Workgroup: 256 threads = 32 q-rows x 8 col-groups; key tiles of 32.
__global__ __launch_bounds__(256) void k_attn(const float* __restrict__ Q,
                                              const float* __restrict__ K,
                                              const float* __restrict__ V,
                                              const int* __restrict__ mask,
                                              float* __restrict__ O, int s) {
    int qt = blockIdx.x;
    int bh = blockIdx.y;
    int h = bh % HH, b = bh / HH;
    __shared__ float Qs[32][132];
    __shared__ float Ks[32][132];
    __shared__ float Vs[32][132];
    __shared__ float Ps[32][33];
    __shared__ float mrow[32], lrow[32], srow[32];
    int tid = threadIdx.x;
    int r = tid >> 3, cg = tid & 7;

    for (int f = tid; f < 32 * 32; f += 256) {   // Q tile: 32 rows x 32 float4
        int rr = f >> 5, c4 = f & 31;
        ((f4*)&Qs[rr][0])[c4] =
            *(const f4*)(Q + (size_t)(b * s + qt * 32 + rr) * DD + h * DHH + c4 * 4);
    }
    if (tid < 32) { mrow[tid] = -3.4e38f; lrow[tid] = 0.f; }
    float acc[16];
#pragma unroll
    for (int i = 0; i < 16; i++) acc[i] = 0.f;
    const float scale = 0.08838834764831845f;    // 1/sqrt(128)

    for (int kt = 0; kt <= qt; kt++) {
        __syncthreads();
        for (int f = tid; f < 32 * 32; f += 256) {
            int rr = f >> 5, c4 = f & 31;
            size_t g = (size_t)(b * s + kt * 32 + rr) * DD + h * DHH + c4 * 4;
            ((f4*)&Ks[rr][0])[c4] = *(const f4*)(K + g);
            ((f4*)&Vs[rr][0])[c4] = *(const f4*)(V + g);
        }
        __syncthreads();
        {   // scores: thread -> rows r, j = cg + 8x (bank-conflict-free)
            float s0 = 0, s1 = 0, s2 = 0, s3 = 0;
            for (int k = 0; k < DHH; k++) {
                float qv = Qs[r][k];
                s0 += qv * Ks[cg + 0][k];
                s1 += qv * Ks[cg + 8][k];
                s2 += qv * Ks[cg + 16][k];
                s3 += qv * Ks[cg + 24][k];
            }
            int ig = qt * 32 + r;
            float sv[4] = {s0, s1, s2, s3};
#pragma unroll
            for (int x = 0; x < 4; x++) {
                int j = cg + 8 * x;
                int jg = kt * 32 + j;
                bool ok = (jg <= ig) && (mask[b * s + jg] > 0);
                Ps[r][j] = ok ? sv[x] * scale : -1e9f;
            }
        }
        __syncthreads();
        if (tid < 32) {   // per-row online softmax state
            int rr = tid;
            float m_old = mrow[rr];
            float mx = m_old;
            for (int j = 0; j < 32; j++) mx = fmaxf(mx, Ps[rr][j]);
            float scl = expf(m_old - mx);         // 0 when m_old = -inf
            float sum = 0.f;
            for (int j = 0; j < 32; j++) {
                float pv = expf(Ps[rr][j] - mx);
                Ps[rr][j] = pv;
                sum += pv;
            }
            lrow[rr] = lrow[rr] * scl + sum;
            mrow[rr] = mx;
            srow[rr] = scl;
        }
        __syncthreads();
        float scl = srow[r];
#pragma unroll
        for (int cc = 0; cc < 16; cc++) acc[cc] *= scl;
        for (int j = 0; j < 32; j++) {
            float pv = Ps[r][j];
#pragma unroll
            for (int cc = 0; cc < 16; cc++) acc[cc] += pv * Vs[j][cg + cc * 8];
        }
    }
    __syncthreads();
    float linv = 1.0f / lrow[r];
    size_t ob = (size_t)(b * s + qt * 32 + r) * DD + h * DHH;
#pragma unroll
    for (int cc = 0; cc < 16; cc++) O[ob + cg + cc * 8] = acc[cc] * linv;
}

// ---------------- prune scoring / selection ----------------
__global__ __launch_bounds__(256) void k_score(const float* __restrict__ Hb,
                                               const float* __restrict__ srow,
                                               float* __restrict__ sc) {
    int row = blockIdx.x;
    const float* xr = Hb + (size_t)row * DD;
    float ss = 0.f;
    for (int i = threadIdx.x; i < DD / 4; i += blockDim.x) {
        f4 a = ((const f4*)xr)[i];
        f4 w = ((const f4*)srow)[i];
        ss += a.x * w.x + a.y * w.y + a.z * w.z + a.w * w.w;
    }
    for (int o = 32; o > 0; o >>= 1) ss += __shfl_down(ss, o);
    __shared__ float red[4];
    int wid = threadIdx.x >> 6, lane = threadIdx.x & 63;
    if (lane == 0) red[wid] = ss;
    __syncthreads();
    if (threadIdx.x == 0) sc[row] = red[0] + red[1] + red[2] + red[3];
}

// selected iff rank (by value desc, index asc on ties) < kk  — exact top_k semantics
__global__ __launch_bounds__(256) void k_rank(const float* __restrict__ sc,
                                              int* __restrict__ flg, int s, int kk) {
    int b = blockIdx.x / s, i = blockIdx.x % s;
    const float* scb = sc + (size_t)b * s;
    float vi = scb[i];
    int cnt = 0;
    for (int j = threadIdx.x; j < s; j += 256) {
        float vj = scb[j];
        if (vj > vi || (vj == vi && j < i)) cnt++;
    }
    for (int o = 32; o > 0; o >>= 1) cnt += __shfl_down(cnt, o);
    __shared__ int red[4];
    int wid = threadIdx.x >> 6, lane = threadIdx.x & 63;
    if (lane == 0) red[wid] = cnt;
    __syncthreads();
    if (threadIdx.x == 0) flg[b * s + i] = ((red[0] + red[1] + red[2] + red[3]) < kk) ? 1 : 0;
}

__global__ void k_compact(const int* __restrict__ flg, int* __restrict__ idx, int s, int kk) {
    int b = blockIdx.x;
    if (threadIdx.x == 0) {
        int p = 0;
        for (int i = 0; i < s; i++)
            if (flg[b * s + i]) idx[b * kk + (p++)] = i;
    }
}

__global__ void k_gather(const float* __restrict__ Hin, const int* __restrict__ idx,
                         float* __restrict__ Hout, int s, int kk) {
    int row = blockIdx.x;    // b*kk
    int b = row / kk, p = row % kk;
    int i = idx[b * kk + p];
    const f4* src = (const f4*)(Hin + (size_t)(b * s + i) * DD);
    f4* dst = (f4*)(Hout + (size_t)row * DD);
    for (int t = threadIdx.x; t < DD / 4; t += blockDim.x) dst[t] = src[t];
}

__global__ void k_gather_mask(const int* __restrict__ Min, const int* __restrict__ idx,
                              int* __restrict__ Mout, int s, int kk) {
    int t = blockIdx.x * blockDim.x + threadIdx.x;
    if (t < BBATCH * kk) {
        int b = t / kk, p = t % kk;
        Mout[t] = Min[b * s + idx[b * kk + p]];
    }
}

// ---------------------------------------------------------------------------
extern "C" void kernel_launch(void* const* d_in, const int* in_sizes, int n_in,
                              void* d_out, int out_size, void* d_ws, size_t ws_size,
                              hipStream_t stream) {
    const int*   input_ids = (const int*)d_in[0];
    const int*   attn_mask = (const int*)d_in[1];
    const float* embed     = (const float*)d_in[2];
    const float* wq        = (const float*)d_in[3];
    const float* wk        = (const float*)d_in[4];
    const float* wv        = (const float*)d_in[5];
    const float* wo        = (const float*)d_in[6];
    const float* wg        = (const float*)d_in[7];
    const float* wu        = (const float*)d_in[8];
    const float* wd        = (const float*)d_in[9];
    const float* ln1       = (const float*)d_in[10];
    const float* ln2       = (const float*)d_in[11];
    const float* lnf       = (const float*)d_in[12];
    const float* lm_head   = (const float*)d_in[13];
    const float* scorer    = (const float*)d_in[14];

    float* ws = (float*)d_ws;
    const size_t R_HD = (size_t)BBATCH * SSEQ * DD;   // 8,388,608 floats
    float* H0  = ws;
    float* H1  = ws + R_HD;
    float* CQ  = ws + 2 * R_HD;
    float* CK  = ws + 3 * R_HD;
    float* CV  = ws + 4 * R_HD;
    float* OB  = ws + 5 * R_HD;
    float* COS = ws + 6 * R_HD;                 // SSEQ*64
    float* SIN = COS + SSEQ * 64;
    float* SC  = SIN + SSEQ * 64;               // B*S
    int*   FLG = (int*)(SC + (size_t)BBATCH * SSEQ);
    int*   IDX = FLG + BBATCH * SSEQ;
    int*   M0  = IDX + BBATCH * SSEQ;
    int*   M1  = M0 + BBATCH * SSEQ;
    float* FFB = CQ;                            // alias: free during MLP phase

    k_rope_table<<<(SSEQ * 64 + 255) / 256, 256, 0, stream>>>(COS, SIN);
    k_embed<<<BBATCH * SSEQ, 256, 0, stream>>>(input_ids, embed, H0);
    k_copy_int<<<(BBATCH * SSEQ + 255) / 256, 256, 0, stream>>>(attn_mask, M0, BBATCH * SSEQ);

    float* Hc = H0; float* Nc = H1;
    int*   Mc = M0; int*   Mt = M1;
    int s = SSEQ;

    for (int l = 0; l < LLAYERS; l++) {
        if (l == 1 || l == 2) {
            int pi = l - 1;
            int kk = s / 2;
            k_score<<<BBATCH * s, 256, 0, stream>>>(Hc, scorer + (size_t)pi * 2 * DD, SC);
            k_rank<<<BBATCH * s, 256, 0, stream>>>(SC, FLG, s, kk);
            k_compact<<<BBATCH, 64, 0, stream>>>(FLG, IDX, s, kk);
            k_gather<<<BBATCH * kk, 256, 0, stream>>>(Hc, IDX, Nc, s, kk);
            k_gather_mask<<<(BBATCH * kk + 255) / 256, 256, 0, stream>>>(Mc, IDX, Mt, s, kk);
            { float* t = Hc; Hc = Nc; Nc = t; }
            { int* t = Mc; Mc = Mt; Mt = t; }
            s = kk;
        }
        int rows = BBATCH * s;
        const float* Wq = wq + (size_t)l * DD * DD;
        const float* Wk = wk + (size_t)l * DD * DD;
        const float* Wv = wv + (size_t)l * DD * DD;
        const float* Wo = wo + (size_t)l * DD * DD;
        const float* Wg = wg + (size_t)l * DD * FFF;
        const float* Wu = wu + (size_t)l * DD * FFF;
        const float* Wd = wd + (size_t)l * FFF * DD;
        const float* L1 = ln1 + (size_t)l * DD;
        const float* L2 = ln2 + (size_t)l * DD;

        k_rmsnorm<<<rows, 256, 0, stream>>>(Hc, L1, Nc);
        dim3 g1(DD / 64, rows / 64);
        k_gemm<0><<<g1, 256, 0, stream>>>(Nc, Wq, CQ, CQ, rows, DD, DD);
        k_gemm<0><<<g1, 256, 0, stream>>>(Nc, Wk, CK, CK, rows, DD, DD);
        k_gemm<0><<<g1, 256, 0, stream>>>(Nc, Wv, CV, CV, rows, DD, DD);
        k_rope<<<rows * HH, 64, 0, stream>>>(CQ, CK, COS, SIN, s);
        k_attn<<<dim3(s / 32, BBATCH * HH), 256, 0, stream>>>(CQ, CK, CV, Mc, OB, s);
        k_gemm<1><<<g1, 256, 0, stream>>>(OB, Wo, Hc, Hc, rows, DD, DD);

        k_rmsnorm<<<rows, 256, 0, stream>>>(Hc, L2, Nc);
        int nch = rows / 1024;
        for (int c = 0; c < nch; c++) {
            size_t r0 = (size_t)c * 1024;
            dim3 g2(FFF / 64, 1024 / 64);
            k_gemm_dual<<<g2, 256, 0, stream>>>(Nc + r0 * DD, Wg, Wu, FFB, 1024, FFF, DD);
            dim3 g3(DD / 64, 1024 / 64);
            k_gemm<1><<<g3, 256, 0, stream>>>(FFB, Wd, Hc + r0 * DD, Hc + r0 * DD, 1024, DD, FFF);
        }
    }

    // final rmsnorm + lm_head
    int rows = BBATCH * s;   // 1024
    k_rmsnorm<<<rows, 256, 0, stream>>>(Hc, lnf, Nc);
    dim3 gf(VV / 64, rows / 64);
    k_gemm<0><<<gf, 256, 0, stream>>>(Nc, lm_head, (float*)d_out, (float*)d_out, rows, VV, DD);
}

// Round 2
// 10845.579 us; speedup vs baseline: 2.3350x; 2.3350x over previous
//
#include <hip/hip_runtime.h>
#include <math.h>

// ---------------------------------------------------------------------------
// SDTP forward, round 2: bf16x2-split MFMA GEMMs + register-tiled fp32 attn.
// V=32000 D=2048 L=4 H=16 FF=8192 B=2 S=2048 DH=128, prune@{1,2} keep 50%.
// Precision plan: layers 0-3 GEMMs = 3-pass bf16x2 (rel err ~5e-6, safe for
// top-k prune whose median score gaps are ~1.2e-3*sigma); lm_head = 1-pass
// bf16 (post-prune, output-only). Attention exact fp32.
// ---------------------------------------------------------------------------

#define DD 2048
#define HH 16
#define DHH 128
#define FFF 8192
#define BBATCH 2
#define SSEQ 2048
#define VV 32000
#define LLAYERS 4

typedef float4 f4;
typedef __attribute__((ext_vector_type(8))) short short8;   // 8 bf16 = 4 VGPR
typedef __attribute__((ext_vector_type(4))) float f32x4;

__device__ inline unsigned short bf16rne(float x) {
    unsigned u = __float_as_uint(x);
    unsigned r = (u + 0x7FFFu + ((u >> 16) & 1u)) >> 16;
    return (unsigned short)r;
}
__device__ inline float bf16tof(unsigned short h) {
    return __uint_as_float(((unsigned)h) << 16);
}

// ---------------- embedding gather ----------------
__global__ void k_embed(const int* __restrict__ ids, const float* __restrict__ emb,
                        float* __restrict__ out) {
    int row = blockIdx.x;
    int id  = ids[row];
    const f4* src = (const f4*)(emb + (size_t)id * DD);
    f4*       dst = (f4*)(out + (size_t)row * DD);
    for (int i = threadIdx.x; i < DD / 4; i += blockDim.x) dst[i] = src[i];
}

__global__ void k_copy_int(const int* __restrict__ src, int* __restrict__ dst, int n) {
    int i = blockIdx.x * blockDim.x + threadIdx.x;
    if (i < n) dst[i] = src[i];
}

// ---------------- rmsnorm ----------------
__global__ __launch_bounds__(256) void k_rmsnorm(const float* __restrict__ x,
                                                 const float* __restrict__ w,
                                                 float* __restrict__ out) {
    int row = blockIdx.x;
    const float* xr = x + (size_t)row * DD;
    float ss = 0.f;
    for (int i = threadIdx.x; i < DD / 4; i += blockDim.x) {
        f4 v = ((const f4*)xr)[i];
        ss += v.x * v.x + v.y * v.y + v.z * v.z + v.w * v.w;
    }
    for (int o = 32; o > 0; o >>= 1) ss += __shfl_down(ss, o);
    __shared__ float red[4];
    int wid = threadIdx.x >> 6, lane = threadIdx.x & 63;
    if (lane == 0) red[wid] = ss;
    __syncthreads();
    float tot = red[0] + red[1] + red[2] + red[3];
    float inv = 1.0f / sqrtf(tot / (float)DD + 1e-6f);
    float* orow = out + (size_t)row * DD;
    for (int i = threadIdx.x; i < DD / 4; i += blockDim.x) {
        f4 v = ((const f4*)xr)[i];
        f4 wv = ((const f4*)w)[i];
        f4 o;
        o.x = v.x * wv.x * inv; o.y = v.y * wv.y * inv;
        o.z = v.z * wv.z * inv; o.w = v.w * wv.w * inv;
        ((f4*)orow)[i] = o;
    }
}

// ---------------- MFMA GEMM (bf16 / bf16x2-split) ----------------
// C[M,N] = A[M,K] @ W1[K,N]   (+R)   or  silu(A@W1)*(A@W2) if DUAL.
// PASSES: 1 = plain bf16 (hi only); 3 = bf16x2 split (hi*hi + hi*lo + lo*hi).
// Block 128x128, BK=32, 4 waves (2x2), wave tile 64x64 = 4x4 mfma 16x16x32.
// LDS layouts are 16B-chunk XOR-swizzled; reader/writer use identical formula.
template <int PASSES, int RES, int DUAL>
__global__ __launch_bounds__(256, 2) void k_mfma(const float* __restrict__ A,
                                                 const float* __restrict__ W1,
                                                 const float* __restrict__ W2,
                                                 const float* __restrict__ Rsrc,
                                                 float* __restrict__ C,
                                                 int M, int N, int K) {
    constexpr int PL = (PASSES > 1) ? 2 : 1;
    constexpr int NW = DUAL ? 2 : 1;
    __shared__ unsigned short As[PL][128 * 32];       // [m][k] bf16, swizzled
    __shared__ unsigned short Bs[NW][PL][128 * 32];   // [n][k] bf16, swizzled

    int tid = threadIdx.x;
    int m0 = blockIdx.y * 128, n0 = blockIdx.x * 128;
    int w = tid >> 6, lane = tid & 63;
    int wm = w >> 1, wn = w & 1;
    int lr = lane & 15, lq = lane >> 4;
    int aChunk = lq ^ (lr & 3);        // = (k>>3) ^ (row&3) with k=(lq*8)
    int bChunk = lq ^ ((lr >> 2) & 3); // = (k>>3) ^ ((row>>2)&3)

    f32x4 acc[NW][4][4];
#pragma unroll
    for (int u = 0; u < NW; u++)
#pragma unroll
        for (int i = 0; i < 4; i++)
#pragma unroll
            for (int j = 0; j < 4; j++)
#pragma unroll
                for (int r = 0; r < 4; r++) acc[u][i][j][r] = 0.f;

    const int tA_m = tid >> 3;        // 0..31 (rows per pass)
    const int tA_k = (tid & 7) * 4;   // 0..28
    const int tB_n = (tid & 31) * 4;  // 0..124
    const int tB_k = (tid >> 5) * 4;  // 0..28

    for (int k0 = 0; k0 < K; k0 += 32) {
        __syncthreads();
        // ---- stage A tile 128x32 (fp32 -> bf16 hi/lo), coalesced loads ----
#pragma unroll
        for (int p = 0; p < 4; p++) {
            int m = p * 32 + tA_m;
            f4 v = *(const f4*)(A + (size_t)(m0 + m) * K + k0 + tA_k);
            int ch = (tA_k >> 3) ^ (m & 3);
            int idx = m * 32 + ch * 8 + (tA_k & 7);
            ushort4 hv;
            hv.x = bf16rne(v.x); hv.y = bf16rne(v.y);
            hv.z = bf16rne(v.z); hv.w = bf16rne(v.w);
            *(ushort4*)&As[0][idx] = hv;
            if constexpr (PASSES > 1) {
                ushort4 lv;
                lv.x = bf16rne(v.x - bf16tof(hv.x));
                lv.y = bf16rne(v.y - bf16tof(hv.y));
                lv.z = bf16rne(v.z - bf16tof(hv.z));
                lv.w = bf16rne(v.w - bf16tof(hv.w));
                *(ushort4*)&As[1][idx] = lv;
            }
        }
        // ---- stage B tile 32x128 transposed -> Bs[n][k] ----
#pragma unroll
        for (int u = 0; u < NW; u++) {
            const float* Wp = (u == 0) ? W1 : W2;
            float bb[4][4];
#pragma unroll
            for (int i = 0; i < 4; i++) {
                f4 v = *(const f4*)(Wp + (size_t)(k0 + tB_k + i) * N + n0 + tB_n);
                bb[i][0] = v.x; bb[i][1] = v.y; bb[i][2] = v.z; bb[i][3] = v.w;
            }
#pragma unroll
            for (int j = 0; j < 4; j++) {
                int row = tB_n + j;
                int ch = (tB_k >> 3) ^ ((row >> 2) & 3);
                int idx = row * 32 + ch * 8 + (tB_k & 7);
                ushort4 hv;
                hv.x = bf16rne(bb[0][j]); hv.y = bf16rne(bb[1][j]);
                hv.z = bf16rne(bb[2][j]); hv.w = bf16rne(bb[3][j]);
                *(ushort4*)&Bs[u][0][idx] = hv;
                if constexpr (PASSES > 1) {
                    ushort4 lv;
                    lv.x = bf16rne(bb[0][j] - bf16tof(hv.x));
                    lv.y = bf16rne(bb[1][j] - bf16tof(hv.y));
                    lv.z = bf16rne(bb[2][j] - bf16tof(hv.z));
                    lv.w = bf16rne(bb[3][j] - bf16tof(hv.w));
                    *(ushort4*)&Bs[u][1][idx] = lv;
                }
            }
        }
        __syncthreads();
        // ---- fragment loads + MFMA ----
        short8 ah[4], al[4];
#pragma unroll
        for (int i = 0; i < 4; i++) {
            int row = wm * 64 + i * 16 + lr;
            ah[i] = *(const short8*)&As[0][row * 32 + aChunk * 8];
            if constexpr (PASSES > 1)
                al[i] = *(const short8*)&As[1][row * 32 + aChunk * 8];
        }
#pragma unroll
        for (int u = 0; u < NW; u++) {
#pragma unroll
            for (int j = 0; j < 4; j++) {
                int row = wn * 64 + j * 16 + lr;
                short8 bh = *(const short8*)&Bs[u][0][row * 32 + bChunk * 8];
#pragma unroll
                for (int i = 0; i < 4; i++)
                    acc[u][i][j] = __builtin_amdgcn_mfma_f32_16x16x32_bf16(
                        ah[i], bh, acc[u][i][j], 0, 0, 0);
                if constexpr (PASSES > 1) {
                    short8 bl = *(const short8*)&Bs[u][1][row * 32 + bChunk * 8];
#pragma unroll
                    for (int i = 0; i < 4; i++) {
                        acc[u][i][j] = __builtin_amdgcn_mfma_f32_16x16x32_bf16(
                            ah[i], bl, acc[u][i][j], 0, 0, 0);
                        acc[u][i][j] = __builtin_amdgcn_mfma_f32_16x16x32_bf16(
                            al[i], bh, acc[u][i][j], 0, 0, 0);
                    }
                }
            }
        }
    }
    // ---- epilogue: C/D layout col=lane&15, row=(lane>>4)*4+reg ----
#pragma unroll
    for (int i = 0; i < 4; i++) {
#pragma unroll
        for (int j = 0; j < 4; j++) {
            int gm = m0 + wm * 64 + i * 16 + lq * 4;
            int gn = n0 + wn * 64 + j * 16 + lr;
#pragma unroll
            for (int r = 0; r < 4; r++) {
                size_t off = (size_t)(gm + r) * N + gn;
                float vv;
                if constexpr (DUAL) {
                    float g = acc[0][i][j][r], uu = acc[1][i][j][r];
                    vv = g / (1.0f + expf(-g)) * uu;
                } else {
                    vv = acc[0][i][j][r];
                }
                if constexpr (RES) vv += Rsrc[off];
                C[off] = vv;
            }
        }
    }
}

// ---------------- RoPE table (match numpy fp32 dataflow) ----------------
__global__ void k_rope_table(float* __restrict__ cosT, float* __restrict__ sinT) {
    int idx = blockIdx.x * blockDim.x + threadIdx.x;
    if (idx >= SSEQ * 64) return;
    int pos = idx >> 6, d = idx & 63;
    float p   = (float)pow(10000.0, (double)d * (1.0 / 64.0));
    float inv = 1.0f / p;
    float ang = (float)pos * inv;
    cosT[idx] = (float)cos((double)ang);
    sinT[idx] = (float)sin((double)ang);
}

__global__ void k_rope(float* __restrict__ Cq, float* __restrict__ Ck,
                       const float* __restrict__ cosT, const float* __restrict__ sinT,
                       int s) {
    int bi = blockIdx.x;
    int h = bi % HH;
    int i = (bi / HH) % s;
    size_t base = (size_t)(bi / HH) * DD + h * DHH;
    int d = threadIdx.x;
    float c  = cosT[i * 64 + d];
    float sn = sinT[i * 64 + d];
    float x1 = Cq[base + d], x2 = Cq[base + 64 + d];
    Cq[base + d]      = x1 * c - x2 * sn;
    Cq[base + 64 + d] = x1 * sn + x2 * c;
    x1 = Ck[base + d]; x2 = Ck[base + 64 + d];
    Ck[base + d]      = x1 * c - x2 * sn;
    Ck[base + 64 + d] = x1 * sn + x2 * c;
}

// ---------------- flash attention fp32, register-tiled ----------------
// Q-tile 64 rows, K-tile 32. 256 thr: tx=tid&15, ty=tid>>4.
// QK: thread owns rows 4ty..+3, cols 2tx..+1.  PV: rows 4ty..+3, cols {4tx..+3, 64+4tx..+3}.
// Wave-parallel online softmax via shfl_xor across the 16 tx lanes of a row.
__global__ __launch_bounds__(256, 2) void k_attn(const float* __restrict__ Q,
                                                 const float* __restrict__ K,
                                                 const float* __restrict__ V,
                                                 const int* __restrict__ mask,
                                                 float* __restrict__ O, int s) {
    int qt = blockIdx.x, bh = blockIdx.y;
    int h = bh & (HH - 1), b = bh >> 4;
    __shared__ float Qs[64][132];
    __shared__ float Ks[32 * 128];    // chunk-swizzled: elem(c,k) at c*128 + (((k>>2)^(c>>1))*4 + (k&3))
    __shared__ float Vs[32][132];
    __shared__ float Ps[64][36];
    __shared__ float mrow[64], lrow[64];
    int tid = threadIdx.x;
    int tx = tid & 15, ty = tid >> 4;

    // load Q tile
#pragma unroll
    for (int p = 0; p < 2; p++) {
        int r = p * 32 + (tid >> 3);
        int kb = (tid & 7) * 4;
        const float* src = Q + (size_t)(b * s + qt * 64 + r) * DD + h * DHH;
#pragma unroll
        for (int q = 0; q < 4; q++)
            *(f4*)&Qs[r][kb + 32 * q] = *(const f4*)(src + kb + 32 * q);
    }
    if (tid < 64) { mrow[tid] = -3.0e38f; lrow[tid] = 0.f; }

    float acc[4][8];
#pragma unroll
    for (int i = 0; i < 4; i++)
#pragma unroll
        for (int c = 0; c < 8; c++) acc[i][c] = 0.f;
    const float scale = 0.08838834764831845f;  // 1/sqrt(128)

    int ktmax = 2 * (qt + 1);
    for (int kt = 0; kt < ktmax; kt++) {
        __syncthreads();
        // stage K (swizzled) and V (padded)
#pragma unroll
        for (int p = 0; p < 4; p++) {
            int c = p * 8 + (tid >> 5);
            int kk = (tid & 31) * 4;
            size_t g = (size_t)(b * s + kt * 32 + c) * DD + h * DHH + kk;
            f4 kv = *(const f4*)(K + g);
            int ch = (kk >> 2) ^ (c >> 1);
            *(f4*)&Ks[c * 128 + ch * 4] = kv;
            *(f4*)&Vs[c][kk] = *(const f4*)(V + g);
        }
        __syncthreads();
        // ---- QK^T ----
        float sv[4][2];
#pragma unroll
        for (int i = 0; i < 4; i++) { sv[i][0] = 0.f; sv[i][1] = 0.f; }
        for (int kk = 0; kk < 128; kk += 4) {
            f4 qv[4];
#pragma unroll
            for (int i = 0; i < 4; i++) qv[i] = *(const f4*)&Qs[ty * 4 + i][kk];
#pragma unroll
            for (int j = 0; j < 2; j++) {
                int c = tx * 2 + j;
                int ch = (kk >> 2) ^ (c >> 1);
                f4 kv = *(const f4*)&Ks[c * 128 + ch * 4];
#pragma unroll
                for (int i = 0; i < 4; i++)
                    sv[i][j] += qv[i].x * kv.x + qv[i].y * kv.y +
                                qv[i].z * kv.z + qv[i].w * kv.w;
            }
        }
        // ---- mask + wave-parallel online softmax ----
        float scl[4];
#pragma unroll
        for (int i = 0; i < 4; i++) {
            int r = ty * 4 + i;
            int igl = qt * 64 + r;
#pragma unroll
            for (int j = 0; j < 2; j++) {
                int jg = kt * 32 + tx * 2 + j;
                bool ok = (jg <= igl) && (mask[b * s + jg] > 0);
                sv[i][j] = ok ? sv[i][j] * scale : -1.0e9f;
            }
            float rmax = fmaxf(sv[i][0], sv[i][1]);
            rmax = fmaxf(rmax, __shfl_xor(rmax, 1));
            rmax = fmaxf(rmax, __shfl_xor(rmax, 2));
            rmax = fmaxf(rmax, __shfl_xor(rmax, 4));
            rmax = fmaxf(rmax, __shfl_xor(rmax, 8));
            float mold = mrow[r];
            float mnew = fmaxf(mold, rmax);
            float p0 = expf(sv[i][0] - mnew);
            float p1 = expf(sv[i][1] - mnew);
            float ps = p0 + p1;
            ps += __shfl_xor(ps, 1);
            ps += __shfl_xor(ps, 2);
            ps += __shfl_xor(ps, 4);
            ps += __shfl_xor(ps, 8);
            scl[i] = expf(mold - mnew);
            if (tx == 0) { mrow[r] = mnew; lrow[r] = lrow[r] * scl[i] + ps; }
            float2 pw; pw.x = p0; pw.y = p1;
            *(float2*)&Ps[r][tx * 2] = pw;
        }
        __syncthreads();
        // ---- PV ----
#pragma unroll
        for (int i = 0; i < 4; i++) {
            float sc = scl[i];
#pragma unroll
            for (int c = 0; c < 8; c++) acc[i][c] *= sc;
        }
        for (int jj = 0; jj < 32; jj += 4) {
            f4 pv[4];
#pragma unroll
            for (int i = 0; i < 4; i++) pv[i] = *(const f4*)&Ps[ty * 4 + i][jj];
#pragma unroll
            for (int j2 = 0; j2 < 4; j2++) {
                f4 va = *(const f4*)&Vs[jj + j2][tx * 4];
                f4 vb = *(const f4*)&Vs[jj + j2][64 + tx * 4];
#pragma unroll
                for (int i = 0; i < 4; i++) {
                    float p = (&pv[i].x)[j2];
                    acc[i][0] += p * va.x; acc[i][1] += p * va.y;
                    acc[i][2] += p * va.z; acc[i][3] += p * va.w;
                    acc[i][4] += p * vb.x; acc[i][5] += p * vb.y;
                    acc[i][6] += p * vb.z; acc[i][7] += p * vb.w;
                }
            }
        }
    }
    __syncthreads();
#pragma unroll
    for (int i = 0; i < 4; i++) {
        int r = ty * 4 + i;
        float linv = 1.0f / lrow[r];
        size_t ob = (size_t)(b * s + qt * 64 + r) * DD + h * DHH;
        f4 o1, o2;
        o1.x = acc[i][0] * linv; o1.y = acc[i][1] * linv;
        o1.z = acc[i][2] * linv; o1.w = acc[i][3] * linv;
        o2.x = acc[i][4] * linv; o2.y = acc[i][5] * linv;
        o2.z = acc[i][6] * linv; o2.w = acc[i][7] * linv;
        *(f4*)(O + ob + tx * 4) = o1;
        *(f4*)(O + ob + 64 + tx * 4) = o2;
    }
}

// ---------------- prune scoring / selection ----------------
__global__ __launch_bounds__(256) void k_score(const float* __restrict__ Hb,
                                               const float* __restrict__ srow,
                                               float* __restrict__ sc) {
    int row = blockIdx.x;
    const float* xr = Hb + (size_t)row * DD;
    float ss = 0.f;
    for (int i = threadIdx.x; i < DD / 4; i += blockDim.x) {
        f4 a = ((const f4*)xr)[i];
        f4 w = ((const f4*)srow)[i];
        ss += a.x * w.x + a.y * w.y + a.z * w.z + a.w * w.w;
    }
    for (int o = 32; o > 0; o >>= 1) ss += __shfl_down(ss, o);
    __shared__ float red[4];
    int wid = threadIdx.x >> 6, lane = threadIdx.x & 63;
    if (lane == 0) red[wid] = ss;
    __syncthreads();
    if (threadIdx.x == 0) sc[row] = red[0] + red[1] + red[2] + red[3];
}

__global__ __launch_bounds__(256) void k_rank(const float* __restrict__ sc,
                                              int* __restrict__ flg, int s, int kk) {
    int b = blockIdx.x / s, i = blockIdx.x % s;
    const float* scb = sc + (size_t)b * s;
    float vi = scb[i];
    int cnt = 0;
    for (int j = threadIdx.x; j < s; j += 256) {
        float vj = scb[j];
        if (vj > vi || (vj == vi && j < i)) cnt++;
    }
    for (int o = 32; o > 0; o >>= 1) cnt += __shfl_down(cnt, o);
    __shared__ int red[4];
    int wid = threadIdx.x >> 6, lane = threadIdx.x & 63;
    if (lane == 0) red[wid] = cnt;
    __syncthreads();
    if (threadIdx.x == 0) flg[b * s + i] = ((red[0] + red[1] + red[2] + red[3]) < kk) ? 1 : 0;
}

__global__ void k_compact(const int* __restrict__ flg, int* __restrict__ idx, int s, int kk) {
    int b = blockIdx.x;
    if (threadIdx.x == 0) {
        int p = 0;
        for (int i = 0; i < s; i++)
            if (flg[b * s + i]) idx[b * kk + (p++)] = i;
    }
}

__global__ void k_gather(const float* __restrict__ Hin, const int* __restrict__ idx,
                         float* __restrict__ Hout, int s, int kk) {
    int row = blockIdx.x;
    int b = row / kk, p = row % kk;
    int i = idx[b * kk + p];
    const f4* src = (const f4*)(Hin + (size_t)(b * s + i) * DD);
    f4* dst = (f4*)(Hout + (size_t)row * DD);
    for (int t = threadIdx.x; t < DD / 4; t += blockDim.x) dst[t] = src[t];
}

__global__ void k_gather_mask(const int* __restrict__ Min, const int* __restrict__ idx,
                              int* __restrict__ Mout, int s, int kk) {
    int t = blockIdx.x * blockDim.x + threadIdx.x;
    if (t < BBATCH * kk) {
        int b = t / kk, p = t % kk;
        Mout[t] = Min[b * s + idx[b * kk + p]];
    }
}

// ---------------------------------------------------------------------------
extern "C" void kernel_launch(void* const* d_in, const int* in_sizes, int n_in,
                              void* d_out, int out_size, void* d_ws, size_t ws_size,
                              hipStream_t stream) {
    const int*   input_ids = (const int*)d_in[0];
    const int*   attn_mask = (const int*)d_in[1];
    const float* embed     = (const float*)d_in[2];
    const float* wq        = (const float*)d_in[3];
    const float* wk        = (const float*)d_in[4];
    const float* wv        = (const float*)d_in[5];
    const float* wo        = (const float*)d_in[6];
    const float* wg        = (const float*)d_in[7];
    const float* wu        = (const float*)d_in[8];
    const float* wd        = (const float*)d_in[9];
    const float* ln1       = (const float*)d_in[10];
    const float* ln2       = (const float*)d_in[11];
    const float* lnf       = (const float*)d_in[12];
    const float* lm_head   = (const float*)d_in[13];
    const float* scorer    = (const float*)d_in[14];

    float* ws = (float*)d_ws;
    const size_t R_HD = (size_t)BBATCH * SSEQ * DD;
    float* H0  = ws;
    float* H1  = ws + R_HD;
    float* CQ  = ws + 2 * R_HD;
    float* CK  = ws + 3 * R_HD;
    float* CV  = ws + 4 * R_HD;
    float* OB  = ws + 5 * R_HD;
    float* COS = ws + 6 * R_HD;
    float* SIN = COS + SSEQ * 64;
    float* SC  = SIN + SSEQ * 64;
    int*   FLG = (int*)(SC + (size_t)BBATCH * SSEQ);
    int*   IDX = FLG + BBATCH * SSEQ;
    int*   M0  = IDX + BBATCH * SSEQ;
    int*   M1  = M0 + BBATCH * SSEQ;
    float* FFB = CQ;   // alias: CQ free during MLP phase

    k_rope_table<<<(SSEQ * 64 + 255) / 256, 256, 0, stream>>>(COS, SIN);
    k_embed<<<BBATCH * SSEQ, 256, 0, stream>>>(input_ids, embed, H0);
    k_copy_int<<<(BBATCH * SSEQ + 255) / 256, 256, 0, stream>>>(attn_mask, M0, BBATCH * SSEQ);

    float* Hc = H0; float* Nc = H1;
    int*   Mc = M0; int*   Mt = M1;
    int s = SSEQ;

    for (int l = 0; l < LLAYERS; l++) {
        if (l == 1 || l == 2) {
            int pi = l - 1;
            int kk = s / 2;
            k_score<<<BBATCH * s, 256, 0, stream>>>(Hc, scorer + (size_t)pi * 2 * DD, SC);
            k_rank<<<BBATCH * s, 256, 0, stream>>>(SC, FLG, s, kk);
            k_compact<<<BBATCH, 64, 0, stream>>>(FLG, IDX, s, kk);
            k_gather<<<BBATCH * kk, 256, 0, stream>>>(Hc, IDX, Nc, s, kk);
            k_gather_mask<<<(BBATCH * kk + 255) / 256, 256, 0, stream>>>(Mc, IDX, Mt, s, kk);
            { float* t = Hc; Hc = Nc; Nc = t; }
            { int* t = Mc; Mc = Mt; Mt = t; }
            s = kk;
        }
        int rows = BBATCH * s;
        const float* Wq = wq + (size_t)l * DD * DD;
        const float* Wk = wk + (size_t)l * DD * DD;
        const float* Wv = wv + (size_t)l * DD * DD;
        const float* Wo = wo + (size_t)l * DD * DD;
        const float* Wg = wg + (size_t)l * DD * FFF;
        const float* Wu = wu + (size_t)l * DD * FFF;
        const float* Wd = wd + (size_t)l * FFF * DD;
        const float* L1 = ln1 + (size_t)l * DD;
        const float* L2 = ln2 + (size_t)l * DD;

        k_rmsnorm<<<rows, 256, 0, stream>>>(Hc, L1, Nc);
        dim3 g1(DD / 128, rows / 128);
        k_mfma<3, 0, 0><<<g1, 256, 0, stream>>>(Nc, Wq, nullptr, nullptr, CQ, rows, DD, DD);
        k_mfma<3, 0, 0><<<g1, 256, 0, stream>>>(Nc, Wk, nullptr, nullptr, CK, rows, DD, DD);
        k_mfma<3, 0, 0><<<g1, 256, 0, stream>>>(Nc, Wv, nullptr, nullptr, CV, rows, DD, DD);
        k_rope<<<rows * HH, 64, 0, stream>>>(CQ, CK, COS, SIN, s);
        k_attn<<<dim3(s / 64, BBATCH * HH), 256, 0, stream>>>(CQ, CK, CV, Mc, OB, s);
        k_mfma<3, 1, 0><<<g1, 256, 0, stream>>>(OB, Wo, nullptr, Hc, Hc, rows, DD, DD);

        k_rmsnorm<<<rows, 256, 0, stream>>>(Hc, L2, Nc);
        int nch = rows / 1024;
        for (int c = 0; c < nch; c++) {
            size_t r0 = (size_t)c * 1024;
            k_mfma<3, 0, 1><<<dim3(FFF / 128, 1024 / 128), 256, 0, stream>>>(
                Nc + r0 * DD, Wg, Wu, nullptr, FFB, 1024, FFF, DD);
            k_mfma<3, 1, 0><<<dim3(DD / 128, 1024 / 128), 256, 0, stream>>>(
                FFB, Wd, nullptr, Hc + r0 * DD, Hc + r0 * DD, 1024, DD, FFF);
        }
    }

    int rows = BBATCH * s;   // 1024
    k_rmsnorm<<<rows, 256, 0, stream>>>(Hc, lnf, Nc);
    k_mfma<1, 0, 0><<<dim3(VV / 128, rows / 128), 256, 0, stream>>>(
        Nc, lm_head, nullptr, nullptr, (float*)d_out, rows, VV, DD);
}